// Round 13
// baseline (166.440 us; speedup 1.0000x reference)
//
#include <hip/hip_runtime.h>

#define NN 8192
#define BB 4
#define SS 11     // S
#define HHH 11    // H
#define SETQ 32   // SET

typedef unsigned long long u64;
typedef float f4 __attribute__((ext_vector_type(4)));

__device__ __forceinline__ float relu_(float x){ return x > 0.f ? x : 0.f; }
__device__ __forceinline__ float lrelu_(float x){ return x > 0.f ? x : 0.01f*x; }
__device__ __forceinline__ float sigm_(float x){ return 1.f/(1.f + __expf(-x)); }

// ---------------- K0: zero the per-row counters (ws not re-poisoned between replays) ----------------
__global__ void k_zero(int* __restrict__ cnt) {
  cnt[blockIdx.x * 256 + threadIdx.x] = 0;
}

// ---------------- K1: extract — persistent grid-stride stream (copy-shaped) ----------------
// 2048 blocks x 256 threads, 4 independent f4 loads in flight; nonzeros (49K of 64M)
// via atomicAdd position. No ballots, no wave->row mapping, no per-wave teardown.
__global__ __launch_bounds__(256) void k_extract(
    const float* __restrict__ rw, int* __restrict__ cnt,
    int* __restrict__ cols, float* __restrict__ vals) {
  const size_t NF4 = (size_t)NN * NN / 4;       // 16M f4 elements
  const size_t stride = (size_t)2048 * 256;
  size_t tid = (size_t)blockIdx.x * 256 + threadIdx.x;
  #pragma unroll 1
  for (size_t i0 = tid; i0 < NF4; i0 += 4*stride) {
    const size_t i1 = i0 + stride, i2 = i0 + 2*stride, i3 = i0 + 3*stride;
    f4 v0 = *((const f4*)rw + i0);
    f4 v1 = *((const f4*)rw + i1);
    f4 v2 = *((const f4*)rw + i2);
    f4 v3 = *((const f4*)rw + i3);
    f4 vv[4] = {v0, v1, v2, v3};
    size_t ii[4] = {i0, i1, i2, i3};
    #pragma unroll
    for (int g = 0; g < 4; ++g) {
      f4 v = vv[g];
      if ((v.x!=0.f)|(v.y!=0.f)|(v.z!=0.f)|(v.w!=0.f)) {
        size_t base = ii[g] * 4;
        #pragma unroll
        for (int e = 0; e < 4; ++e) {
          float x = v[e];
          if (x != 0.f) {
            int r = (int)((base + e) >> 13);
            int c = (int)((base + e) & (NN-1));
            int pos = atomicAdd(&cnt[r], 1);
            if (pos < 6) { cols[r*6 + pos] = c; vals[r*6 + pos] = x; }
          }
        }
      }
    }
  }
}

// ---------------- K2: enhance + causal conv + k/v projections (level 0) ----------------
// Sorts the <=6 CSR entries by column -> deterministic FP accumulation order.
__global__ void k_enh_kv(const float* __restrict__ occ, const float* __restrict__ prc,
                         const int* __restrict__ cnt, const int* __restrict__ cols,
                         const float* __restrict__ vals,
                         const float* __restrict__ aW, const float* __restrict__ ab,
                         const float* __restrict__ tW, const float* __restrict__ tb,
                         const float* __restrict__ cW, const float* __restrict__ cb,
                         const float* __restrict__ Wk, const float* __restrict__ bk,
                         const float* __restrict__ Wv, const float* __restrict__ bv,
                         float* __restrict__ h_conv,
                         float* __restrict__ kT, float* __restrict__ vT) {
  __shared__ float s_aW[144], s_tW[144], s_ab[12], s_tb[12];
  __shared__ float sWk[121], sWv[121], sbk[11], sbv[11];
  int t = threadIdx.x;
  for (int l = t; l < 144; l += 128) { s_aW[l] = aW[l]; s_tW[l] = tW[l]; }
  for (int l = t; l < 121; l += 128) { sWk[l] = Wk[l]; sWv[l] = Wv[l]; }
  if (t < 12) { s_ab[t] = ab[t]; s_tb[t] = tb[t]; }
  if (t < 11) { sbk[t] = bk[t]; sbv[t] = bv[t]; }
  __syncthreads();
  int idx = blockIdx.x * 128 + t;
  int b = idx >> 13, i = idx & (NN-1);
  int c = cnt[i]; c = c > 6 ? 6 : c;
  int col[6]; float w[6];
  #pragma unroll
  for (int tt = 0; tt < 6; ++tt) {
    col[tt] = tt < c ? cols[i*6+tt] : 0;
    w[tt]   = tt < c ? vals[i*6+tt] : 0.f;
  }
  // insertion-sort first c entries by column (deterministic accumulation order)
  for (int a = 1; a < c; ++a) {
    int cc = col[a]; float vv = w[a];
    int b2 = a - 1;
    while (b2 >= 0 && col[b2] > cc) { col[b2+1] = col[b2]; w[b2+1] = w[b2]; --b2; }
    col[b2+1] = cc; w[b2+1] = vv;
  }
  float rwo[12], rwp[12];
  #pragma unroll
  for (int s = 0; s < 12; ++s) { rwo[s] = 0.f; rwp[s] = 0.f; }
  #pragma unroll
  for (int tt = 0; tt < 6; ++tt) {
    const f4* po = (const f4*)(occ + ((size_t)b*NN + col[tt])*12);
    const f4* pp = (const f4*)(prc + ((size_t)b*NN + col[tt])*12);
    float ww = w[tt];
    #pragma unroll
    for (int s4 = 0; s4 < 3; ++s4) {
      f4 vo = po[s4], vp_ = pp[s4];
      #pragma unroll
      for (int e = 0; e < 4; ++e) { rwo[s4*4+e] += ww*vo[e]; rwp[s4*4+e] += ww*vp_[e]; }
    }
  }
  const f4* xo4 = (const f4*)(occ + (size_t)idx*12);
  const f4* xp4 = (const f4*)(prc + (size_t)idx*12);
  float xo[12], xp[12];
  #pragma unroll
  for (int s4 = 0; s4 < 3; ++s4) {
    f4 vo = xo4[s4], vp_ = xp4[s4];
    #pragma unroll
    for (int e = 0; e < 4; ++e) { xo[s4*4+e] = vo[e]; xp[s4*4+e] = vp_[e]; }
  }
  float oe[12], pe[12];
  #pragma unroll
  for (int s = 0; s < 12; ++s) {
    float atO = s_ab[s], trO = s_tb[s], atP = s_ab[s], trP = s_tb[s];
    #pragma unroll
    for (int u = 0; u < 12; ++u) {
      atO += rwo[u]*s_aW[s*12+u]; trO += rwo[u]*s_tW[s*12+u];
      atP += rwp[u]*s_aW[s*12+u]; trP += rwp[u]*s_tW[s*12+u];
    }
    oe[s] = xo[s] + sigm_(atO)*trO;
    pe[s] = xp[s]*(1.f + sigm_(atP)*trP);
  }
  float c00 = cW[0], c01 = cW[1], c10 = cW[2], c11 = cW[3], cbv = cb[0];
  float h[SS];
  #pragma unroll
  for (int s = 0; s < SS; ++s) {
    h[s] = c00*oe[s] + c01*pe[s] + c10*oe[s+1] + c11*pe[s+1] + cbv;
    h_conv[(size_t)idx*SS + s] = h[s];
  }
  #pragma unroll
  for (int hh = 0; hh < HHH; ++hh) {
    float kk = sbk[hh], vv = sbv[hh];
    #pragma unroll
    for (int u = 0; u < HHH; ++u) { kk += h[u]*sWk[hh*HHH+u]; vv += h[u]*sWv[hh*HHH+u]; }
    kT[((size_t)(b*HHH + hh))*NN + i] = relu_(kk);
    vT[((size_t)(b*HHH + hh))*NN + i] = relu_(vv);
  }
}

// ---------------- K3: mab0 — block per (b,h,q); f4-vectorized ----------------
__global__ void k_mab0(const float* __restrict__ kT, const float* __restrict__ vT,
                       const float* __restrict__ I, const float* __restrict__ W0,
                       const float* __restrict__ b0, float* __restrict__ aw,
                       float* __restrict__ out0) {
  __shared__ float sm[4], ss[4], sa[4];
  int bid = blockIdx.x;
  int q = bid & 31;
  int h = (bid >> 5) % HHH;
  int b = bid / (32*HHH);
  int t = threadIdx.x;
  int lane = t & 63, wid = t >> 6;
  float qv = b0[h];
  #pragma unroll
  for (int u = 0; u < HHH; ++u) qv += I[q*HHH+u]*W0[h*HHH+u];
  qv = relu_(qv);
  const f4* kp = (const f4*)(kT + ((size_t)(b*HHH + h))*NN);
  const f4* vp = (const f4*)(vT + ((size_t)(b*HHH + h))*NN);
  f4 sc[8];
  #pragma unroll
  for (int kk = 0; kk < 8; ++kk) sc[kk] = qv * kp[t + kk*256];
  float m = -3.0e38f;
  #pragma unroll
  for (int kk = 0; kk < 8; ++kk)
    m = fmaxf(m, fmaxf(fmaxf(sc[kk].x, sc[kk].y), fmaxf(sc[kk].z, sc[kk].w)));
  #pragma unroll
  for (int off = 1; off < 64; off <<= 1) m = fmaxf(m, __shfl_xor(m, off));
  if (lane == 0) sm[wid] = m;
  __syncthreads();
  float M = fmaxf(fmaxf(sm[0], sm[1]), fmaxf(sm[2], sm[3]));
  float s = 0.f;
  #pragma unroll
  for (int kk = 0; kk < 8; ++kk) {
    f4 e;
    e.x = __expf(sc[kk].x - M); e.y = __expf(sc[kk].y - M);
    e.z = __expf(sc[kk].z - M); e.w = __expf(sc[kk].w - M);
    sc[kk] = e;
    s += e.x + e.y + e.z + e.w;
  }
  #pragma unroll
  for (int off = 1; off < 64; off <<= 1) s += __shfl_xor(s, off);
  if (lane == 0) ss[wid] = s;
  __syncthreads();
  float rinv = 1.f / (ss[0] + ss[1] + ss[2] + ss[3]);
  f4* ap = (f4*)(aw + ((size_t)((h*BB + b)*SETQ + q))*NN);
  f4 acc4 = {0.f, 0.f, 0.f, 0.f};
  #pragma unroll
  for (int kk = 0; kk < 8; ++kk) {
    f4 a = sc[kk] * rinv;
    __builtin_nontemporal_store(a, ap + t + kk*256);
    acc4 += a * vp[t + kk*256];
  }
  float acc = acc4.x + acc4.y + acc4.z + acc4.w;
  #pragma unroll
  for (int off = 1; off < 64; off <<= 1) acc += __shfl_xor(acc, off);
  if (lane == 0) sa[wid] = acc;
  __syncthreads();
  if (t == 0) out0[(b*SETQ + q)*HHH + h] = sa[0]+sa[1]+sa[2]+sa[3];
}

// ---------------- K4/K6: mab1 — block: 8 rows, all 11 heads; 8 lanes per row ----------------
template<int FIN>
__global__ void k_mab1(const float* __restrict__ X, const float* __restrict__ out0,
                       const float* __restrict__ W, const float* __restrict__ bbp,
                       const float* __restrict__ fpW, const float* __restrict__ fpb,
                       float* __restrict__ aw, float* __restrict__ zout,
                       float* __restrict__ kT2, float* __restrict__ vT2,
                       const float* __restrict__ Wk2, const float* __restrict__ bk2,
                       const float* __restrict__ Wv2, const float* __restrict__ bv2,
                       const float* __restrict__ hc_,
                       const float* __restrict__ tW, const float* __restrict__ tb,
                       const float* __restrict__ f1W, const float* __restrict__ f1b,
                       const float* __restrict__ f2W, const float* __restrict__ f2b,
                       const float* __restrict__ f3W, const float* __restrict__ f3b,
                       float* __restrict__ y) {
  __shared__ float sHs[352], sk[352], sv[352];
  __shared__ float sX[96], sz[96], souts[96];
  __shared__ float sW3[121], sW10[121], sW11[121], sW12[121], sW13[121], sfW[121];
  __shared__ float sWk2[121], sWv2[121];
  __shared__ float sb3[11], sb10[11], sb11[11], sb12[11], sb13[11], sfb[11], sbk2[11], sbv2[11];
  int t = threadIdx.x;
  int blk = blockIdx.x;
  int vb = (blk & 7)*512 + (blk >> 3);   // XCD-contiguous row panels
  int r0 = vb * 8;
  int b = r0 >> 13;
  int i0 = r0 & (NN-1);
  if (t < 121) {
    sW3[t] = W[363+t]; sW10[t] = W[484+t]; sW11[t] = W[484+121+t];
    sW12[t] = W[484+242+t]; sW13[t] = W[484+363+t]; sfW[t] = fpW[t];
    if (!FIN) { sWk2[t] = Wk2[t]; sWv2[t] = Wv2[t]; }
  }
  if (t < 11) {
    sb3[t] = bbp[33+t]; sb10[t] = bbp[44+t]; sb11[t] = bbp[55+t];
    sb12[t] = bbp[66+t]; sb13[t] = bbp[77+t]; sfb[t] = fpb[t];
    if (!FIN) { sbk2[t] = bk2[t]; sbv2[t] = bv2[t]; }
  }
  if (t < 88) sX[t] = X[(size_t)r0*SS + t];
  __syncthreads();
  for (int l = t; l < 352; l += 256) {
    int j = l / 11, hh = l - j*11;
    const float* o = out0 + (b*SETQ + j)*HHH;
    float acc = sb3[hh];
    #pragma unroll
    for (int u = 0; u < HHH; ++u) acc += o[u]*sW3[hh*HHH+u];
    sHs[l] = relu_(acc);
  }
  __syncthreads();
  for (int l = t; l < 352; l += 256) {
    int j = l / 11, hh = l - j*11;
    float a1 = sb11[hh], a2 = sb12[hh];
    #pragma unroll
    for (int u = 0; u < HHH; ++u) { float xx = sHs[j*11+u]; a1 += xx*sW11[hh*HHH+u]; a2 += xx*sW12[hh*HHH+u]; }
    sk[l] = relu_(a1); sv[l] = relu_(a2);
  }
  __syncthreads();
  {
    int wv = t >> 6, lane = t & 63;
    int r = lane >> 3, jg = lane & 7;
    for (int h = wv; h < HHH; h += 4) {
      float qv = sb10[h];
      #pragma unroll
      for (int u = 0; u < HHH; ++u) qv += sX[r*11+u]*sW10[h*HHH+u];
      qv = relu_(qv);
      float sc[4];
      #pragma unroll
      for (int jj = 0; jj < 4; ++jj) sc[jj] = qv*sk[(jg*4+jj)*11 + h];
      float m = fmaxf(fmaxf(sc[0], sc[1]), fmaxf(sc[2], sc[3]));
      m = fmaxf(m, __shfl_xor(m, 1));
      m = fmaxf(m, __shfl_xor(m, 2));
      m = fmaxf(m, __shfl_xor(m, 4));
      float e[4]; float ssum = 0.f;
      #pragma unroll
      for (int jj = 0; jj < 4; ++jj) { e[jj] = __expf(sc[jj]-m); ssum += e[jj]; }
      ssum += __shfl_xor(ssum, 1);
      ssum += __shfl_xor(ssum, 2);
      ssum += __shfl_xor(ssum, 4);
      float rinv = 1.f/ssum;
      f4 av; av.x = e[0]*rinv; av.y = e[1]*rinv; av.z = e[2]*rinv; av.w = e[3]*rinv;
      __builtin_nontemporal_store(av,
          (f4*)(aw + ((size_t)((h*BB + b)*NN + i0 + r))*SETQ + jg*4));
      float acc = av.x*sv[(jg*4+0)*11+h] + av.y*sv[(jg*4+1)*11+h]
                + av.z*sv[(jg*4+2)*11+h] + av.w*sv[(jg*4+3)*11+h];
      acc += __shfl_xor(acc, 1);
      acc += __shfl_xor(acc, 2);
      acc += __shfl_xor(acc, 4);
      if (jg == 0) souts[r*12 + h] = acc;
    }
  }
  __syncthreads();
  if (t < 8) {
    int idx = r0 + t;
    float outm[HHH];
    #pragma unroll
    for (int u = 0; u < HHH; ++u) outm[u] = souts[t*12+u];
    float h1[HHH];
    #pragma unroll
    for (int hh = 0; hh < HHH; ++hh) {
      float acc = sb13[hh];
      #pragma unroll
      for (int u = 0; u < HHH; ++u) acc += outm[u]*sW13[hh*HHH+u];
      h1[hh] = relu_(acc);
    }
    float z[SS];
    #pragma unroll
    for (int s = 0; s < SS; ++s) {
      float acc = sfb[s];
      #pragma unroll
      for (int u = 0; u < SS; ++u) acc += h1[u]*sfW[s*SS+u];
      z[s] = lrelu_(acc);
    }
    if (!FIN) {
      #pragma unroll
      for (int s = 0; s < SS; ++s) {
        zout[(size_t)idx*SS + s] = z[s];
        sz[t*12 + s] = z[s];
      }
    } else {
      float xc[2][SS];
      #pragma unroll
      for (int s = 0; s < SS; ++s) {
        float hv = hc_[(size_t)idx*SS+s];
        float inner = 0.5f*sX[t*11+s] + 0.5f*hv;
        float outer = 0.5f*z[s] + 0.5f*inner;
        xc[0][s] = outer; xc[1][s] = outer;
      }
      #pragma unroll
      for (int blk2 = 0; blk2 < 2; ++blk2) {
        const int dil = 1 << blk2;
        float o1[2][SS], o2[2][SS];
        #pragma unroll
        for (int co = 0; co < 2; ++co) {
          const float* w0 = tW + (((blk2*2+0)*2+co)*2+0)*3;
          const float* w1 = tW + (((blk2*2+0)*2+co)*2+1)*3;
          float bb0 = tb[(blk2*2+0)*2+co];
          #pragma unroll
          for (int tp = 0; tp < SS; ++tp) {
            float acc = bb0 + w0[2]*xc[0][tp] + w1[2]*xc[1][tp];
            if (tp >= dil)   acc += w0[1]*xc[0][tp-dil] + w1[1]*xc[1][tp-dil];
            if (tp >= 2*dil) acc += w0[0]*xc[0][tp-2*dil] + w1[0]*xc[1][tp-2*dil];
            o1[co][tp] = relu_(acc);
          }
        }
        #pragma unroll
        for (int co = 0; co < 2; ++co) {
          const float* w0 = tW + (((blk2*2+1)*2+co)*2+0)*3;
          const float* w1 = tW + (((blk2*2+1)*2+co)*2+1)*3;
          float bb1 = tb[(blk2*2+1)*2+co];
          #pragma unroll
          for (int tp = 0; tp < SS; ++tp) {
            float acc = bb1 + w0[2]*o1[0][tp] + w1[2]*o1[1][tp];
            if (tp >= dil)   acc += w0[1]*o1[0][tp-dil] + w1[1]*o1[1][tp-dil];
            if (tp >= 2*dil) acc += w0[0]*o1[0][tp-2*dil] + w1[0]*o1[1][tp-2*dil];
            o2[co][tp] = relu_(acc);
          }
        }
        #pragma unroll
        for (int co = 0; co < 2; ++co)
          #pragma unroll
          for (int tp = 0; tp < SS; ++tp)
            xc[co][tp] = relu_(o2[co][tp] + xc[co][tp]);
      }
      float ht0 = xc[0][SS-1], ht1 = xc[1][SS-1];
      float Hc[2][6];
      #pragma unroll
      for (int c = 0; c < 2; ++c)
        #pragma unroll
        for (int f = 0; f < 6; ++f) {
          float acc = f1b[f];
          #pragma unroll
          for (int tt = 0; tt < 10; ++tt) acc += xc[c][tt]*f1W[f*10+tt];
          Hc[c][f] = acc;
        }
      float av2[2];
      #pragma unroll
      for (int c = 0; c < 2; ++c) {
        float hn0 = f2b[0], hn1 = f2b[1];
        #pragma unroll
        for (int f = 0; f < 6; ++f) { hn0 += Hc[c][f]*f2W[0*6+f]; hn1 += Hc[c][f]*f2W[1*6+f]; }
        av2[c] = sigm_(hn0*ht0 + hn1*ht1);
      }
      float yv = f3b[0];
      #pragma unroll
      for (int f = 0; f < 6; ++f) yv += f3W[f]*(av2[0]*Hc[0][f] + av2[1]*Hc[1][f]);
      yv += f3W[6]*ht0 + f3W[7]*ht1;
      y[idx] = yv;
    }
  }
  if (!FIN) {
    __syncthreads();
    if (t < 88) {
      int r = t / 11, hh = t - r*11;
      float kk = sbk2[hh], vv = sbv2[hh];
      #pragma unroll
      for (int u = 0; u < HHH; ++u) { float zz = sz[r*12+u]; kk += zz*sWk2[hh*HHH+u]; vv += zz*sWv2[hh*HHH+u]; }
      kT2[((size_t)(b*HHH + hh))*NN + i0 + r] = relu_(kk);
      vT2[((size_t)(b*HHH + hh))*NN + i0 + r] = relu_(vv);
    }
  }
}

extern "C" void kernel_launch(void* const* d_in, const int* in_sizes, int n_in,
                              void* d_out, int out_size, void* d_ws, size_t ws_size,
                              hipStream_t stream) {
  const float* occ    = (const float*)d_in[0];
  const float* prc    = (const float*)d_in[1];
  const float* rw_adj = (const float*)d_in[2];
  const float* rw_t_W = (const float*)d_in[3];
  const float* rw_t_b = (const float*)d_in[4];
  const float* rw_a_W = (const float*)d_in[5];
  const float* rw_a_b = (const float*)d_in[6];
  const float* conv_W = (const float*)d_in[7];
  const float* conv_b = (const float*)d_in[8];
  const float* ba_I   = (const float*)d_in[9];
  const float* ba_W   = (const float*)d_in[10];
  const float* ba_b   = (const float*)d_in[11];
  const float* fp_W   = (const float*)d_in[12];
  const float* fp_b   = (const float*)d_in[13];
  const float* tcn_W  = (const float*)d_in[14];
  const float* tcn_b  = (const float*)d_in[15];
  const float* fc1_W  = (const float*)d_in[16];
  const float* fc1_b  = (const float*)d_in[17];
  const float* fc2_W  = (const float*)d_in[18];
  const float* fc2_b  = (const float*)d_in[19];
  const float* fc3_W  = (const float*)d_in[20];
  const float* fc3_b  = (const float*)d_in[21];

  float* ws = (float*)d_ws;
  int* cnt    = (int*)ws;               // 8192
  int* cols   = (int*)(ws + 8192);      // 49152
  float* vals = ws + 57344;             // 49152
  float* h_conv = ws + 106496;          // 360448
  float* kT   = ws + 466944;            // 360448
  float* vT   = ws + 827392;            // 360448
  float* z1   = ws + 1187840;           // 360448
  float* kT2  = ws + 1548288;           // 360448
  float* vT2  = ws + 1908736;           // 360448
  float* out0a = ws + 2269184;          // 1408
  float* out0b = ws + 2270592;          // 1408

  float* out = (float*)d_out;
  float* y    = out;
  float* aw01 = out + 32768;
  float* aw11 = out + 11567104;
  float* aw02 = out + 23101440;
  float* aw12 = out + 34635776;

  const float* W0  = ba_W;              // level 0 base
  const float* bb0 = ba_b;
  const float* W1  = ba_W + 968;        // level 1 base
  const float* bb1 = ba_b + 88;

  k_zero<<<32, 256, 0, stream>>>(cnt);
  k_extract<<<2048, 256, 0, stream>>>(rw_adj, cnt, cols, vals);
  k_enh_kv<<<256, 128, 0, stream>>>(occ, prc, cnt, cols, vals,
                                    rw_a_W, rw_a_b, rw_t_W, rw_t_b,
                                    conv_W, conv_b,
                                    W0 + 121, bb0 + 11, W0 + 242, bb0 + 22,
                                    h_conv, kT, vT);
  k_mab0<<<BB*HHH*SETQ, 256, 0, stream>>>(kT, vT, ba_I, W0, bb0, aw01, out0a);
  k_mab1<0><<<4096, 256, 0, stream>>>(h_conv, out0a, W0, bb0, fp_W, fp_b,
                                      aw11, z1, kT2, vT2,
                                      W1 + 121, bb1 + 11, W1 + 242, bb1 + 22,
                                      nullptr, nullptr, nullptr,
                                      nullptr, nullptr, nullptr, nullptr,
                                      nullptr, nullptr, nullptr);
  k_mab0<<<BB*HHH*SETQ, 256, 0, stream>>>(kT2, vT2, ba_I + SETQ*HHH, W1, bb1, aw02, out0b);
  k_mab1<1><<<4096, 256, 0, stream>>>(z1, out0b, W1, bb1, fp_W + 121, fp_b + 11,
                                      aw12, nullptr, nullptr, nullptr,
                                      nullptr, nullptr, nullptr, nullptr,
                                      h_conv,
                                      tcn_W, tcn_b, fc1_W, fc1_b,
                                      fc2_W, fc2_b, fc3_W, fc3_b, y);
}

// Round 14
// 126.055 us; speedup vs baseline: 1.3204x; 1.3204x over previous
//
#include <hip/hip_runtime.h>

#define NN 8192
#define BB 4
#define SS 11     // S
#define HHH 11    // H
#define SETQ 32   // SET

typedef unsigned long long u64;
typedef float f4 __attribute__((ext_vector_type(4)));

__device__ __forceinline__ float relu_(float x){ return x > 0.f ? x : 0.f; }
__device__ __forceinline__ float lrelu_(float x){ return x > 0.f ? x : 0.01f*x; }
__device__ __forceinline__ float sigm_(float x){ return 1.f/(1.f + __expf(-x)); }

// ---------------- K1: extract (R11 best-known: wave-per-row, 8KB groups, early exit) ----------------
__global__ __launch_bounds__(256) void k_extract(
    const float* __restrict__ rw, int* __restrict__ cnt,
    int* __restrict__ cols, float* __restrict__ vals) {
  int wave = (blockIdx.x * blockDim.x + threadIdx.x) >> 6;
  int lane = threadIdx.x & 63;
  if (wave >= NN) return;
  const float* row = rw + (size_t)wave * NN;
  int base = 0;
  #pragma unroll 1
  for (int g = 0; g < 4; ++g) {          // 4 iterations x 8KB
    const float* p = row + g*2048 + lane*4;
    f4 v0 = *(const f4*)(p);
    f4 v1 = *(const f4*)(p + 256);
    f4 v2 = *(const f4*)(p + 512);
    f4 v3 = *(const f4*)(p + 768);
    f4 v4 = *(const f4*)(p + 1024);
    f4 v5 = *(const f4*)(p + 1280);
    f4 v6 = *(const f4*)(p + 1536);
    f4 v7 = *(const f4*)(p + 1792);
    bool a0 = (v0.x!=0.f)|(v0.y!=0.f)|(v0.z!=0.f)|(v0.w!=0.f);
    bool a1 = (v1.x!=0.f)|(v1.y!=0.f)|(v1.z!=0.f)|(v1.w!=0.f);
    bool a2 = (v2.x!=0.f)|(v2.y!=0.f)|(v2.z!=0.f)|(v2.w!=0.f);
    bool a3 = (v3.x!=0.f)|(v3.y!=0.f)|(v3.z!=0.f)|(v3.w!=0.f);
    bool a4 = (v4.x!=0.f)|(v4.y!=0.f)|(v4.z!=0.f)|(v4.w!=0.f);
    bool a5 = (v5.x!=0.f)|(v5.y!=0.f)|(v5.z!=0.f)|(v5.w!=0.f);
    bool a6 = (v6.x!=0.f)|(v6.y!=0.f)|(v6.z!=0.f)|(v6.w!=0.f);
    bool a7 = (v7.x!=0.f)|(v7.y!=0.f)|(v7.z!=0.f)|(v7.w!=0.f);
    if (__ballot(a0|a1|a2|a3|a4|a5|a6|a7) != 0ull) {
      f4 vv[8] = {v0, v1, v2, v3, v4, v5, v6, v7};
      bool aa[8] = {a0, a1, a2, a3, a4, a5, a6, a7};
      #pragma unroll
      for (int c = 0; c < 8; ++c) {
        if (__ballot(aa[c]) == 0ull) continue;
        #pragma unroll
        for (int e = 0; e < 4; ++e) {
          float x = vv[c][e];
          u64 m = __ballot(x != 0.0f);
          if (x != 0.0f) {
            int pos = base + __popcll(m & ((1ull << lane) - 1ull));
            if (pos < 6) {
              cols[wave*6 + pos] = g*2048 + c*256 + lane*4 + e;
              vals[wave*6 + pos] = x;
            }
          }
          base += __popcll(m);
        }
      }
      if (base >= 6) break;
    }
  }
  if (lane == 0) cnt[wave] = base > 6 ? 6 : base;
}

// ---------------- K2: enhance + causal conv + k/v projections (level 0) ----------------
__global__ void k_enh_kv(const float* __restrict__ occ, const float* __restrict__ prc,
                         const int* __restrict__ cnt, const int* __restrict__ cols,
                         const float* __restrict__ vals,
                         const float* __restrict__ aW, const float* __restrict__ ab,
                         const float* __restrict__ tW, const float* __restrict__ tb,
                         const float* __restrict__ cW, const float* __restrict__ cb,
                         const float* __restrict__ Wk, const float* __restrict__ bk,
                         const float* __restrict__ Wv, const float* __restrict__ bv,
                         float* __restrict__ h_conv,
                         float* __restrict__ kT, float* __restrict__ vT) {
  __shared__ float s_aW[144], s_tW[144], s_ab[12], s_tb[12];
  __shared__ float sWk[121], sWv[121], sbk[11], sbv[11];
  int t = threadIdx.x;
  for (int l = t; l < 144; l += 128) { s_aW[l] = aW[l]; s_tW[l] = tW[l]; }
  for (int l = t; l < 121; l += 128) { sWk[l] = Wk[l]; sWv[l] = Wv[l]; }
  if (t < 12) { s_ab[t] = ab[t]; s_tb[t] = tb[t]; }
  if (t < 11) { sbk[t] = bk[t]; sbv[t] = bv[t]; }
  __syncthreads();
  int idx = blockIdx.x * 128 + t;
  int b = idx >> 13, i = idx & (NN-1);
  int c = cnt[i];
  int col[6]; float w[6];
  #pragma unroll
  for (int tt = 0; tt < 6; ++tt) {
    col[tt] = tt < c ? cols[i*6+tt] : 0;
    w[tt]   = tt < c ? vals[i*6+tt] : 0.f;
  }
  float rwo[12], rwp[12];
  #pragma unroll
  for (int s = 0; s < 12; ++s) { rwo[s] = 0.f; rwp[s] = 0.f; }
  #pragma unroll
  for (int tt = 0; tt < 6; ++tt) {
    const f4* po = (const f4*)(occ + ((size_t)b*NN + col[tt])*12);
    const f4* pp = (const f4*)(prc + ((size_t)b*NN + col[tt])*12);
    float ww = w[tt];
    #pragma unroll
    for (int s4 = 0; s4 < 3; ++s4) {
      f4 vo = po[s4], vp_ = pp[s4];
      #pragma unroll
      for (int e = 0; e < 4; ++e) { rwo[s4*4+e] += ww*vo[e]; rwp[s4*4+e] += ww*vp_[e]; }
    }
  }
  const f4* xo4 = (const f4*)(occ + (size_t)idx*12);
  const f4* xp4 = (const f4*)(prc + (size_t)idx*12);
  float xo[12], xp[12];
  #pragma unroll
  for (int s4 = 0; s4 < 3; ++s4) {
    f4 vo = xo4[s4], vp_ = xp4[s4];
    #pragma unroll
    for (int e = 0; e < 4; ++e) { xo[s4*4+e] = vo[e]; xp[s4*4+e] = vp_[e]; }
  }
  float oe[12], pe[12];
  #pragma unroll
  for (int s = 0; s < 12; ++s) {
    float atO = s_ab[s], trO = s_tb[s], atP = s_ab[s], trP = s_tb[s];
    #pragma unroll
    for (int u = 0; u < 12; ++u) {
      atO += rwo[u]*s_aW[s*12+u]; trO += rwo[u]*s_tW[s*12+u];
      atP += rwp[u]*s_aW[s*12+u]; trP += rwp[u]*s_tW[s*12+u];
    }
    oe[s] = xo[s] + sigm_(atO)*trO;
    pe[s] = xp[s]*(1.f + sigm_(atP)*trP);
  }
  float c00 = cW[0], c01 = cW[1], c10 = cW[2], c11 = cW[3], cbv = cb[0];
  float h[SS];
  #pragma unroll
  for (int s = 0; s < SS; ++s) {
    h[s] = c00*oe[s] + c01*pe[s] + c10*oe[s+1] + c11*pe[s+1] + cbv;
    h_conv[(size_t)idx*SS + s] = h[s];
  }
  #pragma unroll
  for (int hh = 0; hh < HHH; ++hh) {
    float kk = sbk[hh], vv = sbv[hh];
    #pragma unroll
    for (int u = 0; u < HHH; ++u) { kk += h[u]*sWk[hh*HHH+u]; vv += h[u]*sWv[hh*HHH+u]; }
    kT[((size_t)(b*HHH + hh))*NN + i] = relu_(kk);
    vT[((size_t)(b*HHH + hh))*NN + i] = relu_(vv);
  }
}

// ---------------- K3: mab0 — block per (b,h,q); f4-vectorized ----------------
__global__ void k_mab0(const float* __restrict__ kT, const float* __restrict__ vT,
                       const float* __restrict__ I, const float* __restrict__ W0,
                       const float* __restrict__ b0, float* __restrict__ aw,
                       float* __restrict__ out0) {
  __shared__ float sm[4], ss[4], sa[4];
  int bid = blockIdx.x;
  int q = bid & 31;
  int h = (bid >> 5) % HHH;
  int b = bid / (32*HHH);
  int t = threadIdx.x;
  int lane = t & 63, wid = t >> 6;
  float qv = b0[h];
  #pragma unroll
  for (int u = 0; u < HHH; ++u) qv += I[q*HHH+u]*W0[h*HHH+u];
  qv = relu_(qv);
  const f4* kp = (const f4*)(kT + ((size_t)(b*HHH + h))*NN);
  const f4* vp = (const f4*)(vT + ((size_t)(b*HHH + h))*NN);
  f4 sc[8];
  #pragma unroll
  for (int kk = 0; kk < 8; ++kk) sc[kk] = qv * kp[t + kk*256];
  float m = -3.0e38f;
  #pragma unroll
  for (int kk = 0; kk < 8; ++kk)
    m = fmaxf(m, fmaxf(fmaxf(sc[kk].x, sc[kk].y), fmaxf(sc[kk].z, sc[kk].w)));
  #pragma unroll
  for (int off = 1; off < 64; off <<= 1) m = fmaxf(m, __shfl_xor(m, off));
  if (lane == 0) sm[wid] = m;
  __syncthreads();
  float M = fmaxf(fmaxf(sm[0], sm[1]), fmaxf(sm[2], sm[3]));
  float s = 0.f;
  #pragma unroll
  for (int kk = 0; kk < 8; ++kk) {
    f4 e;
    e.x = __expf(sc[kk].x - M); e.y = __expf(sc[kk].y - M);
    e.z = __expf(sc[kk].z - M); e.w = __expf(sc[kk].w - M);
    sc[kk] = e;
    s += e.x + e.y + e.z + e.w;
  }
  #pragma unroll
  for (int off = 1; off < 64; off <<= 1) s += __shfl_xor(s, off);
  if (lane == 0) ss[wid] = s;
  __syncthreads();
  float rinv = 1.f / (ss[0] + ss[1] + ss[2] + ss[3]);
  f4* ap = (f4*)(aw + ((size_t)((h*BB + b)*SETQ + q))*NN);
  f4 acc4 = {0.f, 0.f, 0.f, 0.f};
  #pragma unroll
  for (int kk = 0; kk < 8; ++kk) {
    f4 a = sc[kk] * rinv;
    __builtin_nontemporal_store(a, ap + t + kk*256);
    acc4 += a * vp[t + kk*256];
  }
  float acc = acc4.x + acc4.y + acc4.z + acc4.w;
  #pragma unroll
  for (int off = 1; off < 64; off <<= 1) acc += __shfl_xor(acc, off);
  if (lane == 0) sa[wid] = acc;
  __syncthreads();
  if (t == 0) out0[(b*SETQ + q)*HHH + h] = sa[0]+sa[1]+sa[2]+sa[3];
}

// ---------------- K4/K6: mab1 — block: 32 rows, all 11 heads; 8 lanes per row ----------------
// 1024 blocks: weight-load + mid-phase + syncs amortized over 4x more rows than R11.
template<int FIN>
__global__ void k_mab1(const float* __restrict__ X, const float* __restrict__ out0,
                       const float* __restrict__ W, const float* __restrict__ bbp,
                       const float* __restrict__ fpW, const float* __restrict__ fpb,
                       float* __restrict__ aw, float* __restrict__ zout,
                       float* __restrict__ kT2, float* __restrict__ vT2,
                       const float* __restrict__ Wk2, const float* __restrict__ bk2,
                       const float* __restrict__ Wv2, const float* __restrict__ bv2,
                       const float* __restrict__ hc_,
                       const float* __restrict__ tW, const float* __restrict__ tb,
                       const float* __restrict__ f1W, const float* __restrict__ f1b,
                       const float* __restrict__ f2W, const float* __restrict__ f2b,
                       const float* __restrict__ f3W, const float* __restrict__ f3b,
                       float* __restrict__ y) {
  __shared__ float sHs[352], sk[352], sv[352];
  __shared__ float sX[352], sz[384], souts[384];
  __shared__ float sW3[121], sW10[121], sW11[121], sW12[121], sW13[121], sfW[121];
  __shared__ float sWk2[121], sWv2[121];
  __shared__ float sb3[11], sb10[11], sb11[11], sb12[11], sb13[11], sfb[11], sbk2[11], sbv2[11];
  int t = threadIdx.x;
  int blk = blockIdx.x;
  int vb = (blk & 7)*128 + (blk >> 3);   // XCD-contiguous row panels (1024 blocks)
  int r0 = vb * 32;                       // 32 rows per block
  int b = r0 >> 13;
  int i0 = r0 & (NN-1);
  if (t < 121) {
    sW3[t] = W[363+t]; sW10[t] = W[484+t]; sW11[t] = W[484+121+t];
    sW12[t] = W[484+242+t]; sW13[t] = W[484+363+t]; sfW[t] = fpW[t];
    if (!FIN) { sWk2[t] = Wk2[t]; sWv2[t] = Wv2[t]; }
  }
  if (t < 11) {
    sb3[t] = bbp[33+t]; sb10[t] = bbp[44+t]; sb11[t] = bbp[55+t];
    sb12[t] = bbp[66+t]; sb13[t] = bbp[77+t]; sfb[t] = fpb[t];
    if (!FIN) { sbk2[t] = bk2[t]; sbv2[t] = bv2[t]; }
  }
  for (int l = t; l < 352; l += 256) sX[l] = X[(size_t)r0*SS + l];   // 32 rows x 11
  __syncthreads();
  for (int l = t; l < 352; l += 256) {
    int j = l / 11, hh = l - j*11;
    const float* o = out0 + (b*SETQ + j)*HHH;
    float acc = sb3[hh];
    #pragma unroll
    for (int u = 0; u < HHH; ++u) acc += o[u]*sW3[hh*HHH+u];
    sHs[l] = relu_(acc);
  }
  __syncthreads();
  for (int l = t; l < 352; l += 256) {
    int j = l / 11, hh = l - j*11;
    float a1 = sb11[hh], a2 = sb12[hh];
    #pragma unroll
    for (int u = 0; u < HHH; ++u) { float xx = sHs[j*11+u]; a1 += xx*sW11[hh*HHH+u]; a2 += xx*sW12[hh*HHH+u]; }
    sk[l] = relu_(a1); sv[l] = relu_(a2);
  }
  __syncthreads();
  {
    int wv = t >> 6, lane = t & 63;
    int rl = lane >> 3, jg = lane & 7;
    for (int h = wv; h < HHH; h += 4) {
      #pragma unroll
      for (int rg = 0; rg < 4; ++rg) {
        int r = rg*8 + rl;                 // row 0..31 within block
        float qv = sb10[h];
        #pragma unroll
        for (int u = 0; u < HHH; ++u) qv += sX[r*11+u]*sW10[h*HHH+u];
        qv = relu_(qv);
        float sc[4];
        #pragma unroll
        for (int jj = 0; jj < 4; ++jj) sc[jj] = qv*sk[(jg*4+jj)*11 + h];
        float m = fmaxf(fmaxf(sc[0], sc[1]), fmaxf(sc[2], sc[3]));
        m = fmaxf(m, __shfl_xor(m, 1));
        m = fmaxf(m, __shfl_xor(m, 2));
        m = fmaxf(m, __shfl_xor(m, 4));
        float e[4]; float ssum = 0.f;
        #pragma unroll
        for (int jj = 0; jj < 4; ++jj) { e[jj] = __expf(sc[jj]-m); ssum += e[jj]; }
        ssum += __shfl_xor(ssum, 1);
        ssum += __shfl_xor(ssum, 2);
        ssum += __shfl_xor(ssum, 4);
        float rinv = 1.f/ssum;
        f4 av; av.x = e[0]*rinv; av.y = e[1]*rinv; av.z = e[2]*rinv; av.w = e[3]*rinv;
        // 64 lanes x 16B = contiguous 1KB lines for rows rg*8..rg*8+7
        __builtin_nontemporal_store(av,
            (f4*)(aw + ((size_t)((h*BB + b)*NN + i0 + r))*SETQ + jg*4));
        float acc = av.x*sv[(jg*4+0)*11+h] + av.y*sv[(jg*4+1)*11+h]
                  + av.z*sv[(jg*4+2)*11+h] + av.w*sv[(jg*4+3)*11+h];
        acc += __shfl_xor(acc, 1);
        acc += __shfl_xor(acc, 2);
        acc += __shfl_xor(acc, 4);
        if (jg == 0) souts[r*12 + h] = acc;
      }
    }
  }
  __syncthreads();
  if (t < 32) {
    int idx = r0 + t;
    float outm[HHH];
    #pragma unroll
    for (int u = 0; u < HHH; ++u) outm[u] = souts[t*12+u];
    float h1[HHH];
    #pragma unroll
    for (int hh = 0; hh < HHH; ++hh) {
      float acc = sb13[hh];
      #pragma unroll
      for (int u = 0; u < HHH; ++u) acc += outm[u]*sW13[hh*HHH+u];
      h1[hh] = relu_(acc);
    }
    float z[SS];
    #pragma unroll
    for (int s = 0; s < SS; ++s) {
      float acc = sfb[s];
      #pragma unroll
      for (int u = 0; u < SS; ++u) acc += h1[u]*sfW[s*SS+u];
      z[s] = lrelu_(acc);
    }
    if (!FIN) {
      #pragma unroll
      for (int s = 0; s < SS; ++s) {
        zout[(size_t)idx*SS + s] = z[s];
        sz[t*12 + s] = z[s];
      }
    } else {
      float xc[2][SS];
      #pragma unroll
      for (int s = 0; s < SS; ++s) {
        float hv = hc_[(size_t)idx*SS+s];
        float inner = 0.5f*sX[t*11+s] + 0.5f*hv;   // sX row == z1 row
        float outer = 0.5f*z[s] + 0.5f*inner;
        xc[0][s] = outer; xc[1][s] = outer;
      }
      #pragma unroll
      for (int blk2 = 0; blk2 < 2; ++blk2) {
        const int dil = 1 << blk2;
        float o1[2][SS], o2[2][SS];
        #pragma unroll
        for (int co = 0; co < 2; ++co) {
          const float* w0 = tW + (((blk2*2+0)*2+co)*2+0)*3;
          const float* w1 = tW + (((blk2*2+0)*2+co)*2+1)*3;
          float bb0 = tb[(blk2*2+0)*2+co];
          #pragma unroll
          for (int tp = 0; tp < SS; ++tp) {
            float acc = bb0 + w0[2]*xc[0][tp] + w1[2]*xc[1][tp];
            if (tp >= dil)   acc += w0[1]*xc[0][tp-dil] + w1[1]*xc[1][tp-dil];
            if (tp >= 2*dil) acc += w0[0]*xc[0][tp-2*dil] + w1[0]*xc[1][tp-2*dil];
            o1[co][tp] = relu_(acc);
          }
        }
        #pragma unroll
        for (int co = 0; co < 2; ++co) {
          const float* w0 = tW + (((blk2*2+1)*2+co)*2+0)*3;
          const float* w1 = tW + (((blk2*2+1)*2+co)*2+1)*3;
          float bb1 = tb[(blk2*2+1)*2+co];
          #pragma unroll
          for (int tp = 0; tp < SS; ++tp) {
            float acc = bb1 + w0[2]*o1[0][tp] + w1[2]*o1[1][tp];
            if (tp >= dil)   acc += w0[1]*o1[0][tp-dil] + w1[1]*o1[1][tp-dil];
            if (tp >= 2*dil) acc += w0[0]*o1[0][tp-2*dil] + w1[0]*o1[1][tp-2*dil];
            o2[co][tp] = relu_(acc);
          }
        }
        #pragma unroll
        for (int co = 0; co < 2; ++co)
          #pragma unroll
          for (int tp = 0; tp < SS; ++tp)
            xc[co][tp] = relu_(o2[co][tp] + xc[co][tp]);
      }
      float ht0 = xc[0][SS-1], ht1 = xc[1][SS-1];
      float Hc[2][6];
      #pragma unroll
      for (int c = 0; c < 2; ++c)
        #pragma unroll
        for (int f = 0; f < 6; ++f) {
          float acc = f1b[f];
          #pragma unroll
          for (int tt = 0; tt < 10; ++tt) acc += xc[c][tt]*f1W[f*10+tt];
          Hc[c][f] = acc;
        }
      float av2[2];
      #pragma unroll
      for (int c = 0; c < 2; ++c) {
        float hn0 = f2b[0], hn1 = f2b[1];
        #pragma unroll
        for (int f = 0; f < 6; ++f) { hn0 += Hc[c][f]*f2W[0*6+f]; hn1 += Hc[c][f]*f2W[1*6+f]; }
        av2[c] = sigm_(hn0*ht0 + hn1*ht1);
      }
      float yv = f3b[0];
      #pragma unroll
      for (int f = 0; f < 6; ++f) yv += f3W[f]*(av2[0]*Hc[0][f] + av2[1]*Hc[1][f]);
      yv += f3W[6]*ht0 + f3W[7]*ht1;
      y[idx] = yv;
    }
  }
  if (!FIN) {
    __syncthreads();
    for (int l = t; l < 352; l += 256) {
      int r = l / 11, hh = l - r*11;
      float kk = sbk2[hh], vv = sbv2[hh];
      #pragma unroll
      for (int u = 0; u < HHH; ++u) { float zz = sz[r*12+u]; kk += zz*sWk2[hh*HHH+u]; vv += zz*sWv2[hh*HHH+u]; }
      kT2[((size_t)(b*HHH + hh))*NN + i0 + r] = relu_(kk);
      vT2[((size_t)(b*HHH + hh))*NN + i0 + r] = relu_(vv);
    }
  }
}

extern "C" void kernel_launch(void* const* d_in, const int* in_sizes, int n_in,
                              void* d_out, int out_size, void* d_ws, size_t ws_size,
                              hipStream_t stream) {
  const float* occ    = (const float*)d_in[0];
  const float* prc    = (const float*)d_in[1];
  const float* rw_adj = (const float*)d_in[2];
  const float* rw_t_W = (const float*)d_in[3];
  const float* rw_t_b = (const float*)d_in[4];
  const float* rw_a_W = (const float*)d_in[5];
  const float* rw_a_b = (const float*)d_in[6];
  const float* conv_W = (const float*)d_in[7];
  const float* conv_b = (const float*)d_in[8];
  const float* ba_I   = (const float*)d_in[9];
  const float* ba_W   = (const float*)d_in[10];
  const float* ba_b   = (const float*)d_in[11];
  const float* fp_W   = (const float*)d_in[12];
  const float* fp_b   = (const float*)d_in[13];
  const float* tcn_W  = (const float*)d_in[14];
  const float* tcn_b  = (const float*)d_in[15];
  const float* fc1_W  = (const float*)d_in[16];
  const float* fc1_b  = (const float*)d_in[17];
  const float* fc2_W  = (const float*)d_in[18];
  const float* fc2_b  = (const float*)d_in[19];
  const float* fc3_W  = (const float*)d_in[20];
  const float* fc3_b  = (const float*)d_in[21];

  float* ws = (float*)d_ws;
  int* cnt    = (int*)ws;               // 8192
  int* cols   = (int*)(ws + 8192);      // 49152
  float* vals = ws + 57344;             // 49152
  float* h_conv = ws + 106496;          // 360448
  float* kT   = ws + 466944;            // 360448
  float* vT   = ws + 827392;            // 360448
  float* z1   = ws + 1187840;           // 360448
  float* kT2  = ws + 1548288;           // 360448
  float* vT2  = ws + 1908736;           // 360448
  float* out0a = ws + 2269184;          // 1408
  float* out0b = ws + 2270592;          // 1408

  float* out = (float*)d_out;
  float* y    = out;
  float* aw01 = out + 32768;
  float* aw11 = out + 11567104;
  float* aw02 = out + 23101440;
  float* aw12 = out + 34635776;

  const float* W0  = ba_W;              // level 0 base
  const float* bb0 = ba_b;
  const float* W1  = ba_W + 968;        // level 1 base
  const float* bb1 = ba_b + 88;

  k_extract<<<2048, 256, 0, stream>>>(rw_adj, cnt, cols, vals);
  k_enh_kv<<<256, 128, 0, stream>>>(occ, prc, cnt, cols, vals,
                                    rw_a_W, rw_a_b, rw_t_W, rw_t_b,
                                    conv_W, conv_b,
                                    W0 + 121, bb0 + 11, W0 + 242, bb0 + 22,
                                    h_conv, kT, vT);
  k_mab0<<<BB*HHH*SETQ, 256, 0, stream>>>(kT, vT, ba_I, W0, bb0, aw01, out0a);
  k_mab1<0><<<1024, 256, 0, stream>>>(h_conv, out0a, W0, bb0, fp_W, fp_b,
                                      aw11, z1, kT2, vT2,
                                      W1 + 121, bb1 + 11, W1 + 242, bb1 + 22,
                                      nullptr, nullptr, nullptr,
                                      nullptr, nullptr, nullptr, nullptr,
                                      nullptr, nullptr, nullptr);
  k_mab0<<<BB*HHH*SETQ, 256, 0, stream>>>(kT2, vT2, ba_I + SETQ*HHH, W1, bb1, aw02, out0b);
  k_mab1<1><<<1024, 256, 0, stream>>>(z1, out0b, W1, bb1, fp_W + 121, fp_b + 11,
                                      aw12, nullptr, nullptr, nullptr,
                                      nullptr, nullptr, nullptr, nullptr,
                                      h_conv,
                                      tcn_W, tcn_b, fc1_W, fc1_b,
                                      fc2_W, fc2_b, fc3_W, fc3_b, y);
}